// Round 1
// baseline (1402.375 us; speedup 1.0000x reference)
//
#include <hip/hip_runtime.h>

// DeepAR forward: B=32, L_IN=336, L_OUT=48, N=512, COV=4, EMB=32, H=64
// T = 383 steps, BN = 16384 sequences. 32 seqs per WG, 512 WGs, persistent.
//
// R3: swapped-operand MFMA (W as A-operand, activations as B-operand).
//  - C/D layout (col=lane&15=seq, row=quad*4+q=hidden) makes each lane own
//    4 consecutive hidden units of ONE seq -> h-store is one ds_write_b64
//    (was 8 scattered ds_write_b16, 4-way conflicts).
//  - 512 threads/WG, 8 waves: wave = (jt = wv>>1 hidden block, mt = wv&1
//    seq tile). acc 16 regs, c-states 8, W0 frags 48 regs, W1 in LDS.
//    VGPR target <=128 -> 4 waves/SIMD (16 waves/CU), 2x occupancy vs R2.
//  - layer-0 bias folded into constant-1.0 columns 133/134 (hi + residual
//    bf16 split keeps f32-level accuracy); layer-1 bias stays f32 in regs.

#define T_STEPS 383
#define AST 168   // A row stride in shorts: [h0 0..63 | h1 64..127 | in 128..132 | 1.0 @133,134 | pad]

typedef __attribute__((ext_vector_type(8))) short short8;
typedef __attribute__((ext_vector_type(4))) short s16x4;
typedef __attribute__((ext_vector_type(4))) float floatx4;

__device__ __forceinline__ unsigned short f2bf(float f){   // RNE (prologue)
  union { float f; unsigned u; } v; v.f = f;
  unsigned u = v.u + 0x7fffu + ((v.u >> 16) & 1u);
  return (unsigned short)(u >> 16);
}
__device__ __forceinline__ unsigned short f2bf_fast(float f){  // round-half-up, 2 instrs
  union { float f; unsigned u; } v; v.f = f;
  return (unsigned short)((v.u + 0x8000u) >> 16);
}
__device__ __forceinline__ float bf2f(unsigned short b){
  union { unsigned u; float f; } v; v.u = ((unsigned)b) << 16; return v.f;
}
__device__ __forceinline__ float fsig(float x){
  return __builtin_amdgcn_rcpf(1.f + __expf(-x));
}
__device__ __forceinline__ float ftanh(float x){
  return 1.f - 2.f * __builtin_amdgcn_rcpf(1.f + __expf(2.f * x));
}

__global__ __launch_bounds__(512, 4) void deepar_kernel(
    const float* __restrict__ hist, const float* __restrict__ fut,
    const float* __restrict__ embW, const float* __restrict__ embB,
    const float* __restrict__ Wih0, const float* __restrict__ Whh0,
    const float* __restrict__ bih0, const float* __restrict__ bhh0,
    const float* __restrict__ Wih1, const float* __restrict__ Whh1,
    const float* __restrict__ bih1, const float* __restrict__ bhh1,
    const float* __restrict__ headW, const float* __restrict__ headB,
    float* __restrict__ outp)
{
  const int tid  = threadIdx.x;
  const int lane = tid & 63;
  const int wv   = tid >> 6;        // 0..7
  const int l15  = lane & 15;
  const int quad = lane >> 4;       // 0..3
  const int koff = quad * 8;
  const int jt   = wv >> 1;         // hidden block (16 cols) 0..3
  const int mt   = wv & 1;          // seq tile 0..1
  const int srow = mt * 16 + l15;   // sequence row this lane owns (as B-col / C-col)
  const int jbase = jt * 16 + quad * 4;  // first of this lane's 4 hidden units

  const int b  = blockIdx.x >> 4;            // batch
  const int n0 = (blockIdx.x & 15) * 32;     // first series index

  __shared__ __align__(16) unsigned short A[32 * AST];
  __shared__ __align__(16) unsigned short W1[64 * 64 * 8];  // 64 frags x 64 lanes x 8 bf16
  __shared__ float HW[128];

  for (int i = tid; i < 32 * AST; i += 512) A[i] = 0;
  if (tid < 128) HW[tid] = headW[tid];
  __syncthreads();   // zero-fill complete before constant/input writes
  if (tid < 32){
    A[tid * AST + 133] = 0x3f80;   // 1.0 (bias-hi column)
    A[tid * AST + 134] = 0x3f80;   // 1.0 (bias-residual column)
  }
  const float hb0 = headB[0], hb1 = headB[1];

  // ---- layer-0 weight A-frags in registers; layer-1 A-frags -> LDS ----
  // A-frag (16x16x32): lane holds A[row = lane&15][k = quad*8 + j], j=0..7
  short8 bf0[4][3];   // [gate][kf]: kf0,1 = Whh0 (k 0..63); kf2 = input cols (k 128..159)
  floatx4 bi1v[4];    // layer-1 bias for this lane's 4 hidden units, per gate
  #pragma unroll
  for (int g = 0; g < 4; ++g){
    const int rf = g * 64 + jt * 16 + l15;     // frag row (gate row)
    float u = 0.f, bb = bih0[rf] + bhh0[rf];
    #pragma unroll
    for (int e = 0; e < 32; ++e){
      float wval = Wih0[rf * 36 + e];
      u  += wval * embW[e];
      bb += wval * embB[e];
    }
    const unsigned short bbq = f2bf(bb);       // bias hi (bf16)
    const float bbr = bb - bf2f(bbq);          // bias residual
    #pragma unroll
    for (int kf = 0; kf < 2; ++kf)
      #pragma unroll
      for (int j = 0; j < 8; ++j)
        bf0[g][kf][j] = (short)f2bf(Whh0[rf * 64 + kf * 32 + koff + j]);
    #pragma unroll
    for (int j = 0; j < 8; ++j){
      const int kk = koff + j;    // local k within input frag; col = 128+kk
      float v = 0.f;
      if (kk == 0) v = u;                                   // prev -> u[rf]
      else if (kk >= 1 && kk <= 4) v = Wih0[rf * 36 + 32 + (kk - 1)];
      else if (kk == 6) v = bbr;                            // residual * 1.0
      unsigned short q16 = (kk == 5) ? bbq : f2bf(v);       // hi * 1.0
      bf0[g][2][j] = (short)q16;
    }
    #pragma unroll
    for (int q = 0; q < 4; ++q){
      const int re = g * 64 + jt * 16 + quad * 4 + q;  // epilogue row (this lane's j)
      bi1v[g][q] = bih1[re] + bhh1[re];
    }
    if (mt == 0){   // one wave per jt fills its W1 frags
      #pragma unroll
      for (int kf = 0; kf < 4; ++kf){
        const float* src = (kf < 2) ? (Wih1 + rf * 64 + kf * 32)
                                    : (Whh1 + rf * 64 + (kf - 2) * 32);
        short8 w;
        #pragma unroll
        for (int j = 0; j < 8; ++j)
          w[j] = (short)f2bf(src[koff + j]);
        *(short8*)&W1[((jt * 16 + g * 4 + kf) * 64 + lane) * 8] = w;
      }
    }
  }

  // ---- input staging (prev: 32 threads; cov: 128 threads) ----
  const bool isPrev = (tid < 32);
  const bool isCov  = (tid >= 64 && tid < 192);
  int ss = 0, cc = 0;
  if (isPrev){ ss = tid; cc = 0; }
  if (isCov) { ss = (tid - 64) >> 2; cc = 1 + ((tid - 64) & 3); }
  const int myN = n0 + ss;

  auto loadSlab = [&](int tt) -> float {
    if (isPrev){
      int l = tt; if (l > 383) l = 383;
      return (l < 336) ? hist[(((size_t)b * 336 + l) * 512 + myN) * 5]
                       : fut [(((size_t)b * 48 + (l - 336)) * 512 + myN) * 5];
    } else if (isCov){
      int l = tt + 1; if (l > 383) l = 383;
      return (l < 336) ? hist[(((size_t)b * 336 + l) * 512 + myN) * 5 + cc]
                       : fut [(((size_t)b * 48 + (l - 336)) * 512 + myN) * 5 + cc];
    }
    return 0.f;
  };

  float rIn = loadSlab(0);
  if (isPrev || isCov) A[ss * AST + 128 + cc] = f2bf(rIn);
  rIn = loadSlab(1);   // prefetch step 1

  float c0s[4], c1s[4];
  #pragma unroll
  for (int i = 0; i < 4; ++i){ c0s[i] = 0.f; c1s[i] = 0.f; }

  const int xbase = srow * AST + koff;    // B-frag read base (shorts)
  const int sbase = srow * AST + jbase;   // h-store base (shorts)

  __syncthreads();

  for (int t = 0; t < T_STEPS; ++t){
    // ================= layer 0 (W as A-op; x-frags at col 0,32,128) ======
    floatx4 acc[4];
    #pragma unroll
    for (int g = 0; g < 4; ++g){ floatx4 z = {0.f, 0.f, 0.f, 0.f}; acc[g] = z; }
    {
      const short8 x0 = *(const short8*)&A[xbase];          // h0(t-1) k 0..31
      const short8 x1 = *(const short8*)&A[xbase + 32];     // h0(t-1) k 32..63
      const short8 x2 = *(const short8*)&A[xbase + 128];    // inputs + bias cols
      #pragma unroll
      for (int g = 0; g < 4; ++g){
        acc[g] = __builtin_amdgcn_mfma_f32_16x16x32_bf16(bf0[g][0], x0, acc[g], 0, 0, 0);
        acc[g] = __builtin_amdgcn_mfma_f32_16x16x32_bf16(bf0[g][1], x1, acc[g], 0, 0, 0);
        acc[g] = __builtin_amdgcn_mfma_f32_16x16x32_bf16(bf0[g][2], x2, acc[g], 0, 0, 0);
      }
    }
    float hn[4];
    #pragma unroll
    for (int q = 0; q < 4; ++q){
      float iv = acc[0][q], fv = acc[1][q];
      float gv = acc[2][q], ov = acc[3][q];
      float c = fsig(fv) * c0s[q] + fsig(iv) * ftanh(gv);
      c0s[q] = c;
      hn[q] = fsig(ov) * ftanh(c);
    }
    __syncthreads();   // B1: all layer-0 reads of A done
    {
      s16x4 pk;
      #pragma unroll
      for (int q = 0; q < 4; ++q) pk[q] = (short)f2bf_fast(hn[q]);
      *(s16x4*)&A[sbase] = pk;            // h0(t): one aligned b64 store
    }
    if (isPrev || isCov) A[ss * AST + 128 + cc] = f2bf_fast(rIn);  // inputs t+1
    rIn = loadSlab(t + 2);                                          // prefetch t+2
    __syncthreads();   // B2: h0 + inputs visible

    // ================= layer 1 (K = h0|h1, cols 0..127; W from LDS) ======
    #pragma unroll
    for (int g = 0; g < 4; ++g) acc[g] = bi1v[g];
    #pragma unroll
    for (int kf = 0; kf < 4; ++kf){
      const short8 xf = *(const short8*)&A[xbase + kf * 32];
      const short8 w0 = *(const short8*)&W1[((jt * 16 +  0 + kf) * 64 + lane) * 8];
      const short8 w1 = *(const short8*)&W1[((jt * 16 +  4 + kf) * 64 + lane) * 8];
      const short8 w2 = *(const short8*)&W1[((jt * 16 +  8 + kf) * 64 + lane) * 8];
      const short8 w3 = *(const short8*)&W1[((jt * 16 + 12 + kf) * 64 + lane) * 8];
      acc[0] = __builtin_amdgcn_mfma_f32_16x16x32_bf16(w0, xf, acc[0], 0, 0, 0);
      acc[1] = __builtin_amdgcn_mfma_f32_16x16x32_bf16(w1, xf, acc[1], 0, 0, 0);
      acc[2] = __builtin_amdgcn_mfma_f32_16x16x32_bf16(w2, xf, acc[2], 0, 0, 0);
      acc[3] = __builtin_amdgcn_mfma_f32_16x16x32_bf16(w3, xf, acc[3], 0, 0, 0);
    }
    #pragma unroll
    for (int q = 0; q < 4; ++q){
      float iv = acc[0][q], fv = acc[1][q];
      float gv = acc[2][q], ov = acc[3][q];
      float c = fsig(fv) * c1s[q] + fsig(iv) * ftanh(gv);
      c1s[q] = c;
      hn[q] = fsig(ov) * ftanh(c);
    }
    __syncthreads();   // B3: all layer-1 reads of h1(t-1) done
    {
      s16x4 pk;
      #pragma unroll
      for (int q = 0; q < 4; ++q) pk[q] = (short)f2bf_fast(hn[q]);
      *(s16x4*)&A[sbase + 64] = pk;       // h1(t)
    }
    // next step's layer-0 reads cols 0..63/128..159 only — no barrier needed
    // until B1; h1 readers (next layer-1) are behind B1+B2.

    // ================= head (only last 48 steps produce output) =========
    if (t >= 335){
      __syncthreads();   // h1 visible for head reads (all 512 threads)
      if (tid < 256){
        const int hs = tid >> 3, outc = (tid >> 2) & 1, part = tid & 3;
        const short8 hv0 = *(const short8*)&A[hs * AST + 64 + part * 16];
        const short8 hv1 = *(const short8*)&A[hs * AST + 64 + part * 16 + 8];
        float p = 0.f;
        #pragma unroll
        for (int jj = 0; jj < 8; ++jj){
          float a0 = fmaxf(bf2f((unsigned short)hv0[jj]), 0.f);
          float a1 = fmaxf(bf2f((unsigned short)hv1[jj]), 0.f);
          p += a0 * HW[outc * 64 + part * 16 + jj];
          p += a1 * HW[outc * 64 + part * 16 + 8 + jj];
        }
        p += __shfl_xor(p, 1);
        p += __shfl_xor(p, 2);
        if ((tid & 3) == 0){
          float val;
          if (outc == 0) val = p + hb0;
          else {
            float x = p + hb1;   // softplus, stable
            val = fmaxf(x, 0.f) + __logf(1.f + __expf(-fabsf(x)));
          }
          outp[(((size_t)b * 48 + (t - 335)) * 512 + (n0 + hs)) * 2 + outc] = val;
        }
      }
    }
  }
}

extern "C" void kernel_launch(void* const* d_in, const int* in_sizes, int n_in,
                              void* d_out, int out_size, void* d_ws, size_t ws_size,
                              hipStream_t stream) {
  (void)in_sizes; (void)n_in; (void)out_size; (void)d_ws; (void)ws_size;
  deepar_kernel<<<dim3(512), dim3(512), 0, stream>>>(
      (const float*)d_in[0],  (const float*)d_in[1],
      (const float*)d_in[2],  (const float*)d_in[3],
      (const float*)d_in[4],  (const float*)d_in[5],
      (const float*)d_in[6],  (const float*)d_in[7],
      (const float*)d_in[8],  (const float*)d_in[9],
      (const float*)d_in[10], (const float*)d_in[11],
      (const float*)d_in[12], (const float*)d_in[13],
      (float*)d_out);
}